// Round 11
// baseline (158.107 us; speedup 1.0000x reference)
//
#include <hip/hip_runtime.h>
#include <hip/hip_fp16.h>
#include <math.h>

// 14-qubit batched statevector sim, MFMA engine. R11: ping-pong state.
// R10 plateaued at ~94 us with VALU diet neutral -> bottleneck is the
// compute-all/barrier/write-all phase serialization per pass (in-place
// permutation hazard), not pipe throughput. Fix: state double-buffered
// (S0/S1, 128 KB), BLOCK=1024 (one 140KB block/CU = same 16 waves/CU as
// R10's 2x512): pass reads S_cur and stores S_next immediately per tile --
// no mid-pass barrier, no out-register arrays; builds into alternating Bc
// planes after stores; ONE barrier per pass (22 -> 11 barriers).
//
// Layouts + circuit mapping byte-identical to R10 (verified):
//   F32: phys = t*512 + ((128*(k>>3) + 8*mlow + (k&7)) ^ swz(t))
//   F_C: phys = tC*256 + ((128*((e>>3)&1) + 8*((e>>4)&15) + (e&7)) ^ swz(tC))
//   B-planes pre-split octet-major: re at 256*(k>>3)+8*n+(k&7), im at +1024.
//   pass = S' = S * U^T complex GEMM via v_mfma_f32_16x16x32_f16; index
//   rotation per pass; ext-ctrl CNOT = B-address flip n^31/n^15 (now wave>=8
//   since mt = wave*2+i, mtC = wave*4+i); wrap CNOT(13,0) deferred; embed +
//   L1-A closed-form rank-1 init; readout fused into last pass.
// LDS: 4*32768 state + 2*4096 Bc + 560 angles = 139824 B (<=160 KB/CU).

#define NQ 14
#define NLAYERS 4
#define NCLASSES 10
#define BLOCK 1024

typedef _Float16 f16;
typedef _Float16 f16x8 __attribute__((ext_vector_type(8)));
typedef _Float16 f16x4 __attribute__((ext_vector_type(4)));
typedef float f32x4 __attribute__((ext_vector_type(4)));
typedef unsigned int u32;
typedef u32 u32x2 __attribute__((ext_vector_type(2)));

__device__ __forceinline__ f32x4 mf(f16x8 a, f16x8 b, f32x4 c) {
  return __builtin_amdgcn_mfma_f32_16x16x32_f16(a, b, c, 0, 0, 0);
}
__device__ __forceinline__ int swz(int t) { return ((t ^ (t >> 3)) & 7) << 3; }

// packed f32x4 -> f16x4 (2x v_cvt_pkrtz_f16_f32)
__device__ __forceinline__ f16x4 cvt4(f32x4 v) {
  u32x2 r;
  r[0] = __builtin_bit_cast(u32, __builtin_amdgcn_cvt_pkrtz(v[0], v[1]));
  r[1] = __builtin_bit_cast(u32, __builtin_amdgcn_cvt_pkrtz(v[2], v[3]));
  return __builtin_bit_cast(f16x4, r);
}

__device__ __forceinline__ int finv5(int n) {
  n ^= ((n >> 3) & 1) << 4;
  n ^= ((n >> 2) & 1) << 3;
  n ^= ((n >> 1) & 1) << 2;
  n ^= (n & 1) << 1;
  return n;
}
__device__ __forceinline__ int finv3(int n) {
  n ^= ((n >> 2) & 1) << 3;
  n ^= ((n >> 1) & 1) << 2;
  n ^= (n & 1) << 1;
  return n;
}

// 32x32 U (RX bits0-4 + 4-CNOT chain), pre-split re/im planes.
__device__ __forceinline__ void build32(f16* Bc, const float* qc, const float* qs,
                                        int base, int tid) {
  const float c0 = qc[base], c1 = qc[base+1], c2 = qc[base+2], c3 = qc[base+3], c4 = qc[base+4];
  const float s0 = qs[base], s1 = qs[base+1], s2 = qs[base+2], s3 = qs[base+3], s4 = qs[base+4];
  if (tid < 1024) {
    const int n = tid >> 5, k = tid & 31;
    const int d = finv5(n) ^ k;
    float mag = ((d & 1) ? s0 : c0) * ((d & 2) ? s1 : c1);
    mag *= ((d & 4) ? s2 : c2) * ((d & 8) ? s3 : c3);
    mag *= ((d & 16) ? s4 : c4);
    const int t = __popc(d) & 3;
    const f16 v = (f16)((t == 1 || t == 2) ? -mag : mag);
    const int p = 256 * (k >> 3) + 8 * n + (k & 7);
    const bool isreal = !(t & 1);
    Bc[p]        = isreal ? v : (f16)0.f;
    Bc[p + 1024] = isreal ? (f16)0.f : v;
  }
}
// 16-col C-plane (RX bits0-3 + 3-chain), k>=16 zero, pre-split.
__device__ __forceinline__ void buildC(f16* Bc, const float* qc, const float* qs,
                                       int base, int tid) {
  const float c0 = qc[base], c1 = qc[base+1], c2 = qc[base+2], c3 = qc[base+3];
  const float s0 = qs[base], s1 = qs[base+1], s2 = qs[base+2], s3 = qs[base+3];
  if (tid < 512) {
    const int n = tid >> 5, k = tid & 31;
    f16 vr = (f16)0.f, vi = (f16)0.f;
    if (k < 16) {
      const int d = finv3(n) ^ k;
      float mag = ((d & 1) ? s0 : c0) * ((d & 2) ? s1 : c1);
      mag *= ((d & 4) ? s2 : c2) * ((d & 8) ? s3 : c3);
      const int t = __popc(d) & 3;
      const f16 v = (f16)((t == 1 || t == 2) ? -mag : mag);
      if (t & 1) vi = v; else vr = v;
    }
    const int p = 256 * (k >> 3) + 8 * n + (k & 7);
    Bc[p]        = vr;
    Bc[p + 1024] = vi;
  }
}

// 5-wire GEMM pass, ping-pong: reads src, stores dst immediately (no barrier).
template<bool CTRL, bool STORE_C>
__device__ __forceinline__ void pass32(const f16* __restrict__ sRe, const f16* __restrict__ sIm,
                                       f16* __restrict__ dRe, f16* __restrict__ dIm,
                                       const f16* __restrict__ BcR, int tid) {
  const int lane = tid & 63, wave = tid >> 6;   // wave in [0,16)
  const int q = lane >> 4, cc = lane & 15;
  int n0 = cc, n1 = cc | 16;
  if (CTRL && wave >= 8) { n0 ^= 31; n1 ^= 31; }   // mt>=16 <=> wave>=8
  const f16x8 br0 = *(const f16x8*)(BcR + 256 * q + 8 * n0);
  const f16x8 bi0 = *(const f16x8*)(BcR + 1024 + 256 * q + 8 * n0);
  const f16x8 br1 = *(const f16x8*)(BcR + 256 * q + 8 * n1);
  const f16x8 bi1 = *(const f16x8*)(BcR + 1024 + 256 * q + 8 * n1);
#pragma unroll
  for (int i = 0; i < 2; ++i) {
    const int mt = wave * 2 + i;                 // [0,32)
    const int pA = mt * 512 + ((128 * q + 8 * cc) ^ swz(mt));
    const f16x8 Ar = *(const f16x8*)(sRe + pA);
    const f16x8 Ai = *(const f16x8*)(sIm + pA);
    const f16x8 nAi = -Ai;
#pragma unroll
    for (int nt = 0; nt < 2; ++nt) {
      const f16x8 br = nt ? br1 : br0;
      const f16x8 bi = nt ? bi1 : bi0;
      f32x4 aR = {0.f,0.f,0.f,0.f}, aI = {0.f,0.f,0.f,0.f};
      aR = mf(Ar, br, aR); aR = mf(nAi, bi, aR);
      aI = mf(Ar, bi, aI); aI = mf(Ai, br, aI);
      const int n5 = nt * 16 + cc;
      int pS;
      if constexpr (STORE_C) {
        const int tC = (mt >> 4) + 2 * n5;
        pS = tC * 256 + ((128 * (q >> 1) + 8 * (mt & 15) + 4 * (q & 1)) ^ swz(tC));
      } else {
        pS = n5 * 512 + ((128 * (2 * (mt & 1) + (q >> 1)) + 8 * (mt >> 1) + 4 * (q & 1)) ^ swz(n5));
      }
      *(f16x4*)(dRe + pS) = cvt4(aR);
      *(f16x4*)(dIm + pS) = cvt4(aI);
    }
  }
}

// 4-wire pass C (K padded to 32). Ext-ctrl (9,10) always (mtC>=32 <=> wave>=8);
// wrap CNOT(13,0) = reg-pair swap at store / p-swap at readout (ctrl = cc bit3).
template<bool FINAL>
__device__ __forceinline__ void passC(const f16* __restrict__ sRe, const f16* __restrict__ sIm,
                                      f16* __restrict__ dRe, f16* __restrict__ dIm,
                                      const f16* __restrict__ BcR, int tid,
                                      float* __restrict__ zloc) {
  const int lane = tid & 63, wave = tid >> 6;
  const int q = lane >> 4, cc = lane & 15;
  int n0 = cc;
  if (wave >= 8) n0 ^= 15;
  const f16x8 br = *(const f16x8*)(BcR + 256 * q + 8 * n0);
  const f16x8 bi = *(const f16x8*)(BcR + 1024 + 256 * q + 8 * n0);
#pragma unroll
  for (int i = 0; i < 4; ++i) {
    const int mtC = wave * 4 + i;                // [0,64)
    const int pA = mtC * 256 + ((128 * (q & 1) + 8 * cc) ^ swz(mtC));
    const f16x8 Ar = *(const f16x8*)(sRe + pA);
    const f16x8 Ai = *(const f16x8*)(sIm + pA);
    const f16x8 nAi = -Ai;
    f32x4 aR = {0.f,0.f,0.f,0.f}, aI = {0.f,0.f,0.f,0.f};
    aR = mf(Ar, br, aR); aR = mf(nAi, bi, aR);
    aI = mf(Ar, bi, aI); aI = mf(Ai, br, aI);
    if constexpr (FINAL) {
      float p0 = aR[0]*aR[0] + aI[0]*aI[0];
      float p1 = aR[1]*aR[1] + aI[1]*aI[1];
      float p2 = aR[2]*aR[2] + aI[2]*aI[2];
      float p3 = aR[3]*aR[3] + aI[3]*aI[3];
      if (cc & 8) { float t = p0; p0 = p1; p1 = t; t = p2; p2 = p3; p3 = t; }
      const float ps = p0 + p1 + p2 + p3;
      zloc[0] += (p0 - p1) + (p2 - p3);
      zloc[1] += (p0 + p1) - (p2 + p3);
      zloc[2] += (q & 1) ? -ps : ps;
      zloc[3] += (q & 2) ? -ps : ps;
#pragma unroll
      for (int w = 0; w < 6; ++w) zloc[4 + w] += ((mtC >> w) & 1) ? -ps : ps;
#pragma unroll
      for (int w = 0; w < 4; ++w) zloc[10 + w] += ((cc >> w) & 1) ? -ps : ps;
    } else {
      if (cc & 8) {
        f32x4 tR = aR, tI = aI;
        aR[0] = tR[1]; aR[1] = tR[0]; aR[2] = tR[3]; aR[3] = tR[2];
        aI[0] = tI[1]; aI[1] = tI[0]; aI[2] = tI[3]; aI[3] = tI[2];
      }
      const int tP = 2 * cc + (mtC >> 5);
      const int pS = tP * 512 +
          ((128 * (2 * (mtC & 1) + (q >> 1)) + 8 * ((mtC >> 1) & 15) + 4 * (q & 1)) ^ swz(tP));
      *(f16x4*)(dRe + pS) = cvt4(aR);
      *(f16x4*)(dIm + pS) = cvt4(aI);
    }
  }
}

__global__ __launch_bounds__(BLOCK, 4) void qsim_kernel(
    const float* __restrict__ x, const float* __restrict__ qp,
    const float* __restrict__ fcw, const float* __restrict__ fcb,
    float* __restrict__ out) {
  extern __shared__ unsigned char smem[];
  f16* S0re = (f16*)smem;                   // [16384]
  f16* S0im = S0re + 16384;
  f16* S1re = S0im + 16384;
  f16* S1im = S1re + 16384;
  f16* Bc0  = S1im + 16384;                 // [2048] re+im planes
  f16* Bc1  = Bc0 + 2048;                   // [2048] (aliased scratch/zpart)
  float* qc = (float*)(Bc1 + 2048);         // [56]
  float* qs = qc + 56;                      // [56]
  float* xc = qs + 56;                      // [14]
  float* xs = xc + 14;                      // [14]

  const int b = blockIdx.x;
  const int tid = threadIdx.x;

  // ---- angles ----
  if (tid < NQ) {
    float sv, cv; sincosf(0.5f * x[b * NQ + tid], &sv, &cv);
    xc[tid] = cv; xs[tid] = sv;
  } else if (tid >= 64 && tid < 64 + NLAYERS * NQ) {
    const int k = tid - 64;
    float sv, cv; sincosf(0.5f * qp[k], &sv, &cv);
    qc[k] = cv; qs[k] = sv;
  }
  __syncthreads();

  // ---- closed-form state at L1-B entry (scratch aliases Bc1) ----
  float* Flo  = (float*)Bc1;        // [32]
  float* psi  = Flo + 32;           // [32]
  float* PsiR = psi + 32;           // [32]
  float* PsiI = PsiR + 32;          // [32]
  if (tid < 32) {
    float f = 1.f;
#pragma unroll
    for (int j = 0; j < 5; ++j) f *= ((tid >> j) & 1) ? xs[5 + j] : xc[5 + j];
    Flo[tid] = f;
  } else if (tid < 64) {
    const int k = tid - 32;
    float f = 1.f;
#pragma unroll
    for (int j = 0; j < 5; ++j) f *= ((k >> j) & 1) ? xs[j] : xc[j];
    psi[k] = f;
  }
  __syncthreads();
  if (tid < 32) {   // Psi = U_L1A * psi
    const float c0 = qc[0], c1 = qc[1], c2 = qc[2], c3 = qc[3], c4 = qc[4];
    const float s0 = qs[0], s1 = qs[1], s2 = qs[2], s3 = qs[3], s4 = qs[4];
    const int a = finv5(tid);
    float ar = 0.f, ai = 0.f;
    for (int k = 0; k < 32; ++k) {
      const int d = a ^ k;
      float mag = ((d & 1) ? s0 : c0) * ((d & 2) ? s1 : c1);
      mag *= ((d & 4) ? s2 : c2) * ((d & 8) ? s3 : c3);
      mag *= ((d & 16) ? s4 : c4);
      mag *= psi[k];
      const int t = __popc(d) & 3;
      if (t == 0) ar += mag; else if (t == 1) ai -= mag;
      else if (t == 2) ar -= mag; else ai += mag;
    }
    PsiR[tid] = ar; PsiI[tid] = ai;
  }
  __syncthreads();
  {  // state -> S0 (F32 layout); amp e = u*32 + 16h + 8kb + j, u=tid>>1, h=tid&1
    const int u = tid >> 1, h = tid & 1;
    float fhi = 1.f;
#pragma unroll
    for (int j = 0; j < 4; ++j) fhi *= ((u >> j) & 1) ? xs[10 + j] : xc[10 + j];
    const float cr = fhi * PsiR[u >> 4], ci = fhi * PsiI[u >> 4];
    const int t = u >> 4;          // e>>9
    const int mlow = u & 15;
    const int sz = swz(t);
#pragma unroll
    for (int kb = 0; kb < 2; ++kb) {
      f16x8 hr, hi;
#pragma unroll
      for (int j = 0; j < 8; ++j) {
        const float F = Flo[16 * h + 8 * kb + j];
        hr[j] = (f16)(F * cr);
        hi[j] = (f16)(F * ci);
      }
      const int pb = t * 512 + ((128 * (2 * h + kb) + 8 * mlow) ^ sz);
      *(f16x8*)(S0re + pb) = hr;
      *(f16x8*)(S0im + pb) = hi;
    }
  }
  build32(Bc0, qc, qs, 0 * NQ + 5, tid);   // U(L1-B) into Bc0 (scratch is Bc1)
  __syncthreads();

  // ---- 11 ping-pong passes, ONE barrier each (build into alternate Bc) ----
  pass32<true, true>(S0re, S0im, S1re, S1im, Bc0, tid);   // L1-B
  buildC (Bc1, qc, qs, 0 * NQ + 10, tid);                 __syncthreads();
  passC<false>(S1re, S1im, S0re, S0im, Bc1, tid, nullptr); // L1-C
  build32(Bc0, qc, qs, 1 * NQ + 0, tid);                  __syncthreads();
  pass32<false, false>(S0re, S0im, S1re, S1im, Bc0, tid); // L2-A
  build32(Bc1, qc, qs, 1 * NQ + 5, tid);                  __syncthreads();
  pass32<true, true>(S1re, S1im, S0re, S0im, Bc1, tid);   // L2-B
  buildC (Bc0, qc, qs, 1 * NQ + 10, tid);                 __syncthreads();
  passC<false>(S0re, S0im, S1re, S1im, Bc0, tid, nullptr); // L2-C
  build32(Bc1, qc, qs, 2 * NQ + 0, tid);                  __syncthreads();
  pass32<false, false>(S1re, S1im, S0re, S0im, Bc1, tid); // L3-A
  build32(Bc0, qc, qs, 2 * NQ + 5, tid);                  __syncthreads();
  pass32<true, true>(S0re, S0im, S1re, S1im, Bc0, tid);   // L3-B
  buildC (Bc1, qc, qs, 2 * NQ + 10, tid);                 __syncthreads();
  passC<false>(S1re, S1im, S0re, S0im, Bc1, tid, nullptr); // L3-C
  build32(Bc0, qc, qs, 3 * NQ + 0, tid);                  __syncthreads();
  pass32<false, false>(S0re, S0im, S1re, S1im, Bc0, tid); // L4-A
  build32(Bc1, qc, qs, 3 * NQ + 5, tid);                  __syncthreads();
  pass32<true, true>(S1re, S1im, S0re, S0im, Bc1, tid);   // L4-B
  buildC (Bc0, qc, qs, 3 * NQ + 10, tid);                 __syncthreads();

  float zloc[NQ];
#pragma unroll
  for (int w = 0; w < NQ; ++w) zloc[w] = 0.f;
  passC<true>(S0re, S0im, nullptr, nullptr, Bc0, tid, zloc); // L4-C fused readout

  // ---- reduce + linear head; zpart in Bc1 (idle) ----
  float* zpart = (float*)Bc1;        // [16*14]
  float* zbuf  = zpart + 16 * NQ;    // [14]
#pragma unroll
  for (int w = 0; w < NQ; ++w) {
#pragma unroll
    for (int off = 32; off > 0; off >>= 1)
      zloc[w] += __shfl_down(zloc[w], off, 64);
  }
  const int wave = tid >> 6, lane = tid & 63;
  if (lane == 0) {
#pragma unroll
    for (int w = 0; w < NQ; ++w) zpart[wave * NQ + w] = zloc[w];
  }
  __syncthreads();
  if (tid < NQ) {
    float a = 0.f;
#pragma unroll
    for (int v = 0; v < 16; ++v) a += zpart[v * NQ + tid];
    zbuf[tid] = a;
  }
  __syncthreads();
  if (tid < NCLASSES) {
    float acc = fcb[tid];
#pragma unroll
    for (int w = 0; w < NQ; ++w) acc = fmaf(zbuf[w], fcw[tid * NQ + w], acc);
    out[b * NCLASSES + tid] = acc;
  }
}

extern "C" void kernel_launch(void* const* d_in, const int* in_sizes, int n_in,
                              void* d_out, int out_size, void* d_ws, size_t ws_size,
                              hipStream_t stream) {
  const float* x   = (const float*)d_in[0];
  const float* qp  = (const float*)d_in[1];
  const float* fcw = (const float*)d_in[2];
  const float* fcb = (const float*)d_in[3];
  float* out = (float*)d_out;
  const int B = in_sizes[0] / NQ;

  const size_t shmem = (size_t)(4 * 16384 + 2 * 2048) * sizeof(f16)
                     + (size_t)(56 + 56 + 14 + 14) * sizeof(float);   // 139824 B
  (void)hipFuncSetAttribute((const void*)qsim_kernel,
                            hipFuncAttributeMaxDynamicSharedMemorySize, (int)shmem);
  qsim_kernel<<<B, BLOCK, shmem, stream>>>(x, qp, fcw, fcb, out);
}

// Round 12
// 148.958 us; speedup vs baseline: 1.0614x; 1.0614x over previous
//
#include <hip/hip_runtime.h>
#include <hip/hip_fp16.h>
#include <math.h>

// 14-qubit batched statevector sim, MFMA engine. R12 = R10 structure (94 us,
// in-place state + mid-pass hazard barrier, builds as separate steps, no
// spill) with ONLY the launch shape changed: BLOCK=1024, 2 blocks/CU ->
// 32 waves/CU = 8 waves/SIMD (hardware max, 2x R10). Evidence: R8/R10 (2x512,
// 4 waves/SIMD) = 94-95 us; R11 (1x1024 ping-pong, fewer barriers) = 111 us
// -> the limiter is resident-wave latency hiding, not barrier count.
// Per-thread work halves (pass32 i<2, passC i<4; out arrays 8->4 regs).
// LDS per block unchanged: 70192 B (2 blocks = 140.4 KB <= 160 KB).
//
// Layouts + circuit mapping byte-identical to R10 (verified):
//   F32: phys = t*512 + ((128*(k>>3) + 8*mlow + (k&7)) ^ swz(t))
//   F_C: phys = tC*256 + ((128*((e>>3)&1) + 8*((e>>4)&15) + (e&7)) ^ swz(tC))
//   B-planes pre-split octet-major: re at 256*(k>>3)+8*n+(k&7), im at +1024.
//   pass = S' = S * U^T complex GEMM via v_mfma_f32_16x16x32_f16; index
//   rotation per pass; ext-ctrl CNOT = B-address flip n^31/n^15 (wave>=8);
//   wrap CNOT(13,0) deferred; embed + L1-A closed-form rank-1 init (R11's
//   1024-thread variant, verified); readout fused into last pass.

#define NQ 14
#define NLAYERS 4
#define NCLASSES 10
#define BLOCK 1024

typedef _Float16 f16;
typedef _Float16 f16x8 __attribute__((ext_vector_type(8)));
typedef _Float16 f16x4 __attribute__((ext_vector_type(4)));
typedef float f32x4 __attribute__((ext_vector_type(4)));
typedef unsigned int u32;
typedef u32 u32x2 __attribute__((ext_vector_type(2)));

__device__ __forceinline__ f32x4 mf(f16x8 a, f16x8 b, f32x4 c) {
  return __builtin_amdgcn_mfma_f32_16x16x32_f16(a, b, c, 0, 0, 0);
}
__device__ __forceinline__ int swz(int t) { return ((t ^ (t >> 3)) & 7) << 3; }

// packed f32x4 -> f16x4 (2x v_cvt_pkrtz_f16_f32)
__device__ __forceinline__ f16x4 cvt4(f32x4 v) {
  u32x2 r;
  r[0] = __builtin_bit_cast(u32, __builtin_amdgcn_cvt_pkrtz(v[0], v[1]));
  r[1] = __builtin_bit_cast(u32, __builtin_amdgcn_cvt_pkrtz(v[2], v[3]));
  return __builtin_bit_cast(f16x4, r);
}

__device__ __forceinline__ int finv5(int n) {
  n ^= ((n >> 3) & 1) << 4;
  n ^= ((n >> 2) & 1) << 3;
  n ^= ((n >> 1) & 1) << 2;
  n ^= (n & 1) << 1;
  return n;
}
__device__ __forceinline__ int finv3(int n) {
  n ^= ((n >> 2) & 1) << 3;
  n ^= ((n >> 1) & 1) << 2;
  n ^= (n & 1) << 1;
  return n;
}

// 32x32 U (RX bits0-4 + 4-CNOT chain), pre-split re/im planes.
__device__ __forceinline__ void build32(f16* Bc, const float* qc, const float* qs,
                                        int base, int tid) {
  const float c0 = qc[base], c1 = qc[base+1], c2 = qc[base+2], c3 = qc[base+3], c4 = qc[base+4];
  const float s0 = qs[base], s1 = qs[base+1], s2 = qs[base+2], s3 = qs[base+3], s4 = qs[base+4];
  if (tid < 1024) {
    const int n = tid >> 5, k = tid & 31;
    const int d = finv5(n) ^ k;
    float mag = ((d & 1) ? s0 : c0) * ((d & 2) ? s1 : c1);
    mag *= ((d & 4) ? s2 : c2) * ((d & 8) ? s3 : c3);
    mag *= ((d & 16) ? s4 : c4);
    const int t = __popc(d) & 3;
    const f16 v = (f16)((t == 1 || t == 2) ? -mag : mag);
    const int p = 256 * (k >> 3) + 8 * n + (k & 7);
    const bool isreal = !(t & 1);
    Bc[p]        = isreal ? v : (f16)0.f;
    Bc[p + 1024] = isreal ? (f16)0.f : v;
  }
}
// 16-col C-plane (RX bits0-3 + 3-chain), k>=16 zero, pre-split.
__device__ __forceinline__ void buildC(f16* Bc, const float* qc, const float* qs,
                                       int base, int tid) {
  const float c0 = qc[base], c1 = qc[base+1], c2 = qc[base+2], c3 = qc[base+3];
  const float s0 = qs[base], s1 = qs[base+1], s2 = qs[base+2], s3 = qs[base+3];
  if (tid < 512) {
    const int n = tid >> 5, k = tid & 31;
    f16 vr = (f16)0.f, vi = (f16)0.f;
    if (k < 16) {
      const int d = finv3(n) ^ k;
      float mag = ((d & 1) ? s0 : c0) * ((d & 2) ? s1 : c1);
      mag *= ((d & 4) ? s2 : c2) * ((d & 8) ? s3 : c3);
      const int t = __popc(d) & 3;
      const f16 v = (f16)((t == 1 || t == 2) ? -mag : mag);
      if (t & 1) vi = v; else vr = v;
    }
    const int p = 256 * (k >> 3) + 8 * n + (k & 7);
    Bc[p]        = vr;
    Bc[p + 1024] = vi;
  }
}

// 5-wire GEMM pass (16 waves: mt = wave*2+i). STORE_C: store into F_C else F32.
template<bool CTRL, bool STORE_C>
__device__ __forceinline__ void pass32(f16* __restrict__ reP, f16* __restrict__ imP,
                                       const f16* __restrict__ BcR, int tid) {
  const int lane = tid & 63, wave = tid >> 6;   // wave in [0,16)
  const int q = lane >> 4, cc = lane & 15;
  int n0 = cc, n1 = cc | 16;
  if (CTRL && wave >= 8) { n0 ^= 31; n1 ^= 31; }   // mt>=16 <=> wave>=8
  const f16x8 br0 = *(const f16x8*)(BcR + 256 * q + 8 * n0);
  const f16x8 bi0 = *(const f16x8*)(BcR + 1024 + 256 * q + 8 * n0);
  const f16x8 br1 = *(const f16x8*)(BcR + 256 * q + 8 * n1);
  const f16x8 bi1 = *(const f16x8*)(BcR + 1024 + 256 * q + 8 * n1);
  f16x4 outR[4], outI[4];
#pragma unroll
  for (int i = 0; i < 2; ++i) {
    const int mt = wave * 2 + i;                 // [0,32)
    const int pA = mt * 512 + ((128 * q + 8 * cc) ^ swz(mt));
    const f16x8 Ar = *(const f16x8*)(reP + pA);
    const f16x8 Ai = *(const f16x8*)(imP + pA);
    const f16x8 nAi = -Ai;
    {
      f32x4 aR = {0.f,0.f,0.f,0.f}, aI = {0.f,0.f,0.f,0.f};
      aR = mf(Ar, br0, aR); aR = mf(nAi, bi0, aR);
      aI = mf(Ar, bi0, aI); aI = mf(Ai, br0, aI);
      outR[i * 2 + 0] = cvt4(aR);
      outI[i * 2 + 0] = cvt4(aI);
    }
    {
      f32x4 aR = {0.f,0.f,0.f,0.f}, aI = {0.f,0.f,0.f,0.f};
      aR = mf(Ar, br1, aR); aR = mf(nAi, bi1, aR);
      aI = mf(Ar, bi1, aI); aI = mf(Ai, br1, aI);
      outR[i * 2 + 1] = cvt4(aR);
      outI[i * 2 + 1] = cvt4(aI);
    }
  }
  __syncthreads();   // all reads done before in-place permuted writes
#pragma unroll
  for (int i = 0; i < 2; ++i) {
    const int mt = wave * 2 + i;
#pragma unroll
    for (int nt = 0; nt < 2; ++nt) {
      const int n5 = nt * 16 + cc;
      int pS;
      if constexpr (STORE_C) {
        const int tC = (mt >> 4) + 2 * n5;
        pS = tC * 256 + ((128 * (q >> 1) + 8 * (mt & 15) + 4 * (q & 1)) ^ swz(tC));
      } else {
        pS = n5 * 512 + ((128 * (2 * (mt & 1) + (q >> 1)) + 8 * (mt >> 1) + 4 * (q & 1)) ^ swz(n5));
      }
      *(f16x4*)(reP + pS) = outR[i * 2 + nt];
      *(f16x4*)(imP + pS) = outI[i * 2 + nt];
    }
  }
}

// 4-wire pass C (16 waves: mtC = wave*4+i). Ext-ctrl (9,10) always (wave>=8);
// wrap CNOT(13,0) = reg-pair swap at store / p-swap at readout (ctrl = cc bit3).
template<bool FINAL>
__device__ __forceinline__ void passC(f16* __restrict__ reP, f16* __restrict__ imP,
                                      const f16* __restrict__ BcR, int tid,
                                      float* __restrict__ zloc) {
  const int lane = tid & 63, wave = tid >> 6;
  const int q = lane >> 4, cc = lane & 15;
  int n0 = cc;
  if (wave >= 8) n0 ^= 15;
  const f16x8 br = *(const f16x8*)(BcR + 256 * q + 8 * n0);
  const f16x8 bi = *(const f16x8*)(BcR + 1024 + 256 * q + 8 * n0);
  f16x4 outR[4], outI[4];
#pragma unroll
  for (int i = 0; i < 4; ++i) {
    const int mtC = wave * 4 + i;                // [0,64)
    const int pA = mtC * 256 + ((128 * (q & 1) + 8 * cc) ^ swz(mtC));
    const f16x8 Ar = *(const f16x8*)(reP + pA);
    const f16x8 Ai = *(const f16x8*)(imP + pA);
    const f16x8 nAi = -Ai;
    f32x4 aR = {0.f,0.f,0.f,0.f}, aI = {0.f,0.f,0.f,0.f};
    aR = mf(Ar, br, aR); aR = mf(nAi, bi, aR);
    aI = mf(Ar, bi, aI); aI = mf(Ai, br, aI);
    if constexpr (FINAL) {
      float p0 = aR[0]*aR[0] + aI[0]*aI[0];
      float p1 = aR[1]*aR[1] + aI[1]*aI[1];
      float p2 = aR[2]*aR[2] + aI[2]*aI[2];
      float p3 = aR[3]*aR[3] + aI[3]*aI[3];
      if (cc & 8) { float t = p0; p0 = p1; p1 = t; t = p2; p2 = p3; p3 = t; }
      const float ps = p0 + p1 + p2 + p3;
      zloc[0] += (p0 - p1) + (p2 - p3);
      zloc[1] += (p0 + p1) - (p2 + p3);
      zloc[2] += (q & 1) ? -ps : ps;
      zloc[3] += (q & 2) ? -ps : ps;
#pragma unroll
      for (int w = 0; w < 6; ++w) zloc[4 + w] += ((mtC >> w) & 1) ? -ps : ps;
#pragma unroll
      for (int w = 0; w < 4; ++w) zloc[10 + w] += ((cc >> w) & 1) ? -ps : ps;
    } else {
      if (cc & 8) {
        f32x4 tR = aR, tI = aI;
        aR[0] = tR[1]; aR[1] = tR[0]; aR[2] = tR[3]; aR[3] = tR[2];
        aI[0] = tI[1]; aI[1] = tI[0]; aI[2] = tI[3]; aI[3] = tI[2];
      }
      outR[i] = cvt4(aR);
      outI[i] = cvt4(aI);
    }
  }
  if constexpr (!FINAL) {
    __syncthreads();
#pragma unroll
    for (int i = 0; i < 4; ++i) {
      const int mtC = wave * 4 + i;
      const int tP = 2 * cc + (mtC >> 5);
      const int pS = tP * 512 +
          ((128 * (2 * (mtC & 1) + (q >> 1)) + 8 * ((mtC >> 1) & 15) + 4 * (q & 1)) ^ swz(tP));
      *(f16x4*)(reP + pS) = outR[i];
      *(f16x4*)(imP + pS) = outI[i];
    }
  }
}

__global__ __launch_bounds__(BLOCK, 8) void qsim_kernel(
    const float* __restrict__ x, const float* __restrict__ qp,
    const float* __restrict__ fcw, const float* __restrict__ fcb,
    float* __restrict__ out) {
  extern __shared__ unsigned char smem[];
  f16* reP = (f16*)smem;                    // [16384]
  f16* imP = reP + 16384;                   // [16384]
  f16* Bc  = imP + 16384;                   // [2048] re+im planes (aliased scratch)
  float* qc = (float*)(Bc + 2048);          // [56]
  float* qs = qc + 56;                      // [56]
  float* xc = qs + 56;                      // [14]
  float* xs = xc + 14;                      // [14]

  const int b = blockIdx.x;
  const int tid = threadIdx.x;

  // ---- angles ----
  if (tid < NQ) {
    float sv, cv; sincosf(0.5f * x[b * NQ + tid], &sv, &cv);
    xc[tid] = cv; xs[tid] = sv;
  } else if (tid >= 64 && tid < 64 + NLAYERS * NQ) {
    const int k = tid - 64;
    float sv, cv; sincosf(0.5f * qp[k], &sv, &cv);
    qc[k] = cv; qs[k] = sv;
  }
  __syncthreads();

  // ---- closed-form state at L1-B entry (scratch aliases Bc) ----
  float* Flo  = (float*)Bc;         // [32]
  float* psi  = Flo + 32;           // [32]
  float* PsiR = psi + 32;           // [32]
  float* PsiI = PsiR + 32;          // [32]
  if (tid < 32) {
    float f = 1.f;
#pragma unroll
    for (int j = 0; j < 5; ++j) f *= ((tid >> j) & 1) ? xs[5 + j] : xc[5 + j];
    Flo[tid] = f;
  } else if (tid < 64) {
    const int k = tid - 32;
    float f = 1.f;
#pragma unroll
    for (int j = 0; j < 5; ++j) f *= ((k >> j) & 1) ? xs[j] : xc[j];
    psi[k] = f;
  }
  __syncthreads();
  if (tid < 32) {   // Psi = U_L1A * psi
    const float c0 = qc[0], c1 = qc[1], c2 = qc[2], c3 = qc[3], c4 = qc[4];
    const float s0 = qs[0], s1 = qs[1], s2 = qs[2], s3 = qs[3], s4 = qs[4];
    const int a = finv5(tid);
    float ar = 0.f, ai = 0.f;
    for (int k = 0; k < 32; ++k) {
      const int d = a ^ k;
      float mag = ((d & 1) ? s0 : c0) * ((d & 2) ? s1 : c1);
      mag *= ((d & 4) ? s2 : c2) * ((d & 8) ? s3 : c3);
      mag *= ((d & 16) ? s4 : c4);
      mag *= psi[k];
      const int t = __popc(d) & 3;
      if (t == 0) ar += mag; else if (t == 1) ai -= mag;
      else if (t == 2) ar -= mag; else ai += mag;
    }
    PsiR[tid] = ar; PsiI[tid] = ai;
  }
  __syncthreads();
  {  // state -> F32 layout; amp e = u*32 + 16h + 8kb + j, u = tid>>1, h = tid&1
    const int u = tid >> 1, h = tid & 1;
    float fhi = 1.f;
#pragma unroll
    for (int j = 0; j < 4; ++j) fhi *= ((u >> j) & 1) ? xs[10 + j] : xc[10 + j];
    const float cr = fhi * PsiR[u >> 4], ci = fhi * PsiI[u >> 4];
    const int t = u >> 4;
    const int mlow = u & 15;
    const int sz = swz(t);
    float Fl[16];
#pragma unroll
    for (int j = 0; j < 16; ++j) Fl[j] = Flo[16 * h + j];
    __syncthreads();   // scratch reads done; Bc free for builds
#pragma unroll
    for (int kb = 0; kb < 2; ++kb) {
      f16x8 hr, hi;
#pragma unroll
      for (int j = 0; j < 8; ++j) {
        const float F = Fl[8 * kb + j];
        hr[j] = (f16)(F * cr);
        hi[j] = (f16)(F * ci);
      }
      const int pb = t * 512 + ((128 * (2 * h + kb) + 8 * mlow) ^ sz);
      *(f16x8*)(reP + pb) = hr;
      *(f16x8*)(imP + pb) = hi;
    }
  }
  build32(Bc, qc, qs, 0 * NQ + 5, tid);   // U(L1-B); scratch reads already fenced
  __syncthreads();

  // ---- 11 GEMM passes, builds as separate steps (R10 structure) ----
  pass32<true, true>(reP, imP, Bc, tid);          __syncthreads(); // L1-B
  buildC(Bc, qc, qs, 0 * NQ + 10, tid);           __syncthreads();
  passC<false>(reP, imP, Bc, tid, nullptr);       __syncthreads(); // L1-C
#pragma unroll
  for (int l = 1; l < NLAYERS; ++l) {
    build32(Bc, qc, qs, l * NQ + 0, tid);         __syncthreads();
    pass32<false, false>(reP, imP, Bc, tid);      __syncthreads(); // A
    build32(Bc, qc, qs, l * NQ + 5, tid);         __syncthreads();
    pass32<true, true>(reP, imP, Bc, tid);        __syncthreads(); // B
    buildC(Bc, qc, qs, l * NQ + 10, tid);         __syncthreads();
    if (l < NLAYERS - 1) {
      passC<false>(reP, imP, Bc, tid, nullptr);   __syncthreads(); // C
    }
  }

  float zloc[NQ];
#pragma unroll
  for (int w = 0; w < NQ; ++w) zloc[w] = 0.f;
  passC<true>(reP, imP, Bc, tid, zloc);           // L4-C fused readout
  __syncthreads();

  // ---- reduce + linear head (zpart aliases Bc) ----
  float* zpart = (float*)Bc;         // [16*14]
  float* zbuf  = zpart + 16 * NQ;    // [14]
#pragma unroll
  for (int w = 0; w < NQ; ++w) {
#pragma unroll
    for (int off = 32; off > 0; off >>= 1)
      zloc[w] += __shfl_down(zloc[w], off, 64);
  }
  const int wave = tid >> 6, lane = tid & 63;
  if (lane == 0) {
#pragma unroll
    for (int w = 0; w < NQ; ++w) zpart[wave * NQ + w] = zloc[w];
  }
  __syncthreads();
  if (tid < NQ) {
    float a = 0.f;
#pragma unroll
    for (int v = 0; v < 16; ++v) a += zpart[v * NQ + tid];
    zbuf[tid] = a;
  }
  __syncthreads();
  if (tid < NCLASSES) {
    float acc = fcb[tid];
#pragma unroll
    for (int w = 0; w < NQ; ++w) acc = fmaf(zbuf[w], fcw[tid * NQ + w], acc);
    out[b * NCLASSES + tid] = acc;
  }
}

extern "C" void kernel_launch(void* const* d_in, const int* in_sizes, int n_in,
                              void* d_out, int out_size, void* d_ws, size_t ws_size,
                              hipStream_t stream) {
  const float* x   = (const float*)d_in[0];
  const float* qp  = (const float*)d_in[1];
  const float* fcw = (const float*)d_in[2];
  const float* fcb = (const float*)d_in[3];
  float* out = (float*)d_out;
  const int B = in_sizes[0] / NQ;

  const size_t shmem = (size_t)(2 * 16384 + 2048) * sizeof(f16)
                     + (size_t)(56 + 56 + 14 + 14) * sizeof(float);   // 70192 B
  (void)hipFuncSetAttribute((const void*)qsim_kernel,
                            hipFuncAttributeMaxDynamicSharedMemorySize, (int)shmem);
  qsim_kernel<<<B, BLOCK, shmem, stream>>>(x, qp, fcw, fcb, out);
}